// Round 1
// baseline (288.327 us; speedup 1.0000x reference)
//
#include <hip/hip_runtime.h>
#include <hip/hip_bf16.h>
#include <stdint.h>

#define V 23
#define VP 24          // v padded (zeros) -> 48B bf16 rows, 96B f32 rows
#define KK 3
#define H 8
#define CG 16          // channels per group (in == out)
#define TDIM 256
#define NB 32
#define TT 64          // t-tile
#define OUTC 128
#define CIN 128

// ws layout (floats):
//   [0, 13824)        BnA padded [K][H][VP][VP]
//   [13824, 13952)    scale[128]  = gamma/sqrt(var+eps)
//   [13952, 14080)    offs[128]   = beta - mean*scale + (sum_k b)*scale
#define WS_BNA   0
#define WS_SCALE (KK*H*VP*VP)
#define WS_OFFS  (WS_SCALE + OUTC)

static __device__ __forceinline__ uint32_t f2bf_rne(float f) {
  uint32_t u = __float_as_uint(f);
  return (u + 0x7fffu + ((u >> 16) & 1u)) >> 16;
}

__global__ void prep_bna_kernel(const float* __restrict__ emb,
                                const float* __restrict__ A,
                                const int* __restrict__ hop,
                                int n_hop, float* __restrict__ bna) {
  int kh = blockIdx.x;          // k*H + h, 0..23
  int w = threadIdx.x;          // 0..31, cols
  if (w >= VP) return;
  const float* e = emb + kh * n_hop;
  const float* a = A + kh * V * V;
  float nb = 1.f, na = 1.f;
  if (w < V) {
    float sb = 0.f, sa = 0.f;
    for (int v = 0; v < V; ++v) {
      float bv = e[hop[v * V + w]];
      float av = a[v * V + w];
      sb += bv * bv;
      sa += av * av;
    }
    nb = sqrtf(sb) + 1e-4f;    // l2 over rows (axis=-2), per column
    na = sqrtf(sa) + 1e-4f;
  }
  float* dst = bna + kh * VP * VP;
  for (int v = 0; v < VP; ++v) {
    float val = 0.f;
    if (v < V && w < V)
      val = e[hop[v * V + w]] / nb + a[v * V + w] / na;
    dst[v * VP + w] = val;     // pad row v=23 and col w=23 are zero
  }
}

__global__ void prep_bn_kernel(const float* __restrict__ conv_b,
                               const float* __restrict__ gamma,
                               const float* __restrict__ beta,
                               const float* __restrict__ mean,
                               const float* __restrict__ var,
                               float* __restrict__ scale_ws,
                               float* __restrict__ offs_ws) {
  int oc = threadIdx.x;        // 0..127
  float inv = gamma[oc] * rsqrtf(var[oc] + 1e-5f);
  float sb = conv_b[oc] + conv_b[OUTC + oc] + conv_b[2 * OUTC + oc];
  scale_ws[oc] = inv;
  offs_ws[oc] = beta[oc] - mean[oc] * inv + sb * inv;
}

__global__ __launch_bounds__(256, 2) void gcn_main(
    const float* __restrict__ x,
    const float* __restrict__ conv_w,
    const float* __restrict__ bna_ws,
    const float* __restrict__ scale_ws,
    const float* __restrict__ offs_ws,
    float* __restrict__ out) {
  // LDS: 49152 + 6912 + 3072 = 59136 B  -> 2 blocks/CU
  __shared__ __align__(16) uint16_t Xs[CG * TT * VP];   // bf16 [c][tt][vp]
  __shared__ __align__(16) float BnAs[KK * VP * VP];    // [k][v][w]
  __shared__ __align__(16) float Ws[KK * CG * CG];      // [k][c][o]  (transposed)

  const int tid = threadIdx.x;
  const int t0 = blockIdx.x * TT;
  const int h  = blockIdx.y;
  const int n  = blockIdx.z;

  // ---- stage BnA slice for this h (432 float4) ----
  {
    const float4* src = (const float4*)bna_ws;
    float4* dst = (float4*)BnAs;
    for (int i = tid; i < KK * (VP * VP / 4); i += 256) {
      int k = i / (VP * VP / 4), r = i % (VP * VP / 4);
      dst[k * (VP * VP / 4) + r] = src[(k * H + h) * (VP * VP / 4) + r];
    }
  }
  // ---- stage W transposed: Ws[k][c][o] = conv_w[(k*128 + h*16 + o)*16 + c] ----
  for (int i = tid; i < KK * CG * CG; i += 256) {
    int k = i >> 8, r = i & 255;
    int c = r >> 4, o = r & 15;
    Ws[(k * CG + c) * CG + o] = conv_w[((k * OUTC) + h * CG + o) * CG + c];
  }
  // ---- stage x -> bf16 LDS, v padded to 24 with zeros ----
  // units: c(16) x tt(64) x vchunk(6 of 4)
  for (int u = tid; u < CG * TT * 6; u += 256) {
    int c = u / (TT * 6);
    int r = u % (TT * 6);
    int tt = r / 6, vc = r % 6;
    const float* xrow =
        x + ((size_t)((n * CIN + h * CG + c) * TDIM) + (t0 + tt)) * V;
    float f0 = xrow[vc * 4 + 0];
    float f1 = xrow[vc * 4 + 1];
    float f2 = xrow[vc * 4 + 2];
    float f3 = (vc < 5) ? xrow[vc * 4 + 3] : 0.f;   // v=23 pad
    uint32_t lo = f2bf_rne(f0) | (f2bf_rne(f1) << 16);
    uint32_t hi = f2bf_rne(f2) | (f2bf_rne(f3) << 16);
    *(uint2*)&Xs[(c * TT + tt) * VP + vc * 4] = make_uint2(lo, hi);
  }
  __syncthreads();

  const int oq = tid >> 6;   // wave id: out-channel quad
  const int tt = tid & 63;

  float acc[4][VP];
#pragma unroll
  for (int o = 0; o < 4; ++o)
#pragma unroll
    for (int w = 0; w < VP; ++w) acc[o][w] = 0.f;

  for (int k = 0; k < KK; ++k) {
    for (int vb = 0; vb < 3; ++vb) {       // 8 v's per chunk (24 incl pad)
      float xwv[4][8];
#pragma unroll
      for (int o = 0; o < 4; ++o)
#pragma unroll
        for (int j = 0; j < 8; ++j) xwv[o][j] = 0.f;

      // stage A: channel mix, xwv[o][j] = sum_c W[k][o][c] * X[c][tt][vb*8+j]
#pragma unroll 4
      for (int c = 0; c < CG; ++c) {
        uint4 raw = *(const uint4*)&Xs[(c * TT + tt) * VP + vb * 8];
        float xv[8];
        xv[0] = __uint_as_float(raw.x << 16);
        xv[1] = __uint_as_float(raw.x & 0xffff0000u);
        xv[2] = __uint_as_float(raw.y << 16);
        xv[3] = __uint_as_float(raw.y & 0xffff0000u);
        xv[4] = __uint_as_float(raw.z << 16);
        xv[5] = __uint_as_float(raw.z & 0xffff0000u);
        xv[6] = __uint_as_float(raw.w << 16);
        xv[7] = __uint_as_float(raw.w & 0xffff0000u);
        float4 wv = *(const float4*)&Ws[(k * CG + c) * CG + (oq << 2)];
#pragma unroll
        for (int o = 0; o < 4; ++o) {
          float wo = (&wv.x)[o];
#pragma unroll
          for (int j = 0; j < 8; ++j) xwv[o][j] = fmaf(wo, xv[j], xwv[o][j]);
        }
      }

      // stage B: spatial mix, acc[o][w] += xwv[o][j] * BnA[k][v][w]
#pragma unroll
      for (int j = 0; j < 8; ++j) {
        const int v = vb * 8 + j;          // v=23 row of BnA is zero -> no-op
        const float* bnrow = &BnAs[(k * VP + v) * VP];
#pragma unroll
        for (int wb = 0; wb < 6; ++wb) {
          float4 bn = *(const float4*)(bnrow + wb * 4);
#pragma unroll
          for (int o = 0; o < 4; ++o) {
            acc[o][wb * 4 + 0] = fmaf(xwv[o][j], bn.x, acc[o][wb * 4 + 0]);
            acc[o][wb * 4 + 1] = fmaf(xwv[o][j], bn.y, acc[o][wb * 4 + 1]);
            acc[o][wb * 4 + 2] = fmaf(xwv[o][j], bn.z, acc[o][wb * 4 + 2]);
            acc[o][wb * 4 + 3] = fmaf(xwv[o][j], bn.w, acc[o][wb * 4 + 3]);
          }
        }
      }
    }
  }

  // ---- epilogue: BN + residual (bf16 from LDS, tol 0.148 allows it) + relu ----
#pragma unroll
  for (int o = 0; o < 4; ++o) {
    int og = (oq << 2) + o;                // 0..15 within group
    int oc = h * CG + og;
    float sc = scale_ws[oc];
    float of = offs_ws[oc];
    float* orow = out + ((size_t)(n * OUTC + oc) * TDIM + (t0 + tt)) * V;
    const uint16_t* xsrow = &Xs[(og * TT + tt) * VP];
#pragma unroll
    for (int w = 0; w < V; ++w) {
      float resid = __uint_as_float(((uint32_t)xsrow[w]) << 16);
      float y = fmaf(acc[o][w], sc, of) + resid;
      orow[w] = fmaxf(y, 0.f);
    }
  }
}

extern "C" void kernel_launch(void* const* d_in, const int* in_sizes, int n_in,
                              void* d_out, int out_size, void* d_ws, size_t ws_size,
                              hipStream_t stream) {
  const float* x      = (const float*)d_in[0];
  const float* emb    = (const float*)d_in[1];
  const float* A      = (const float*)d_in[2];
  const float* conv_w = (const float*)d_in[3];
  const float* conv_b = (const float*)d_in[4];
  const float* gamma  = (const float*)d_in[5];
  const float* beta   = (const float*)d_in[6];
  const float* mean   = (const float*)d_in[7];
  const float* var    = (const float*)d_in[8];
  const int*   hop    = (const int*)d_in[9];
  float* ws  = (float*)d_ws;
  float* out = (float*)d_out;

  int n_hop = in_sizes[1] / (KK * H);

  prep_bna_kernel<<<dim3(KK * H), dim3(32), 0, stream>>>(emb, A, hop, n_hop,
                                                         ws + WS_BNA);
  prep_bn_kernel<<<dim3(1), dim3(OUTC), 0, stream>>>(conv_b, gamma, beta, mean,
                                                     var, ws + WS_SCALE,
                                                     ws + WS_OFFS);
  gcn_main<<<dim3(TDIM / TT, H, NB), dim3(256), 0, stream>>>(
      x, conv_w, ws + WS_BNA, ws + WS_SCALE, ws + WS_OFFS, out);
}

// Round 2
// 287.058 us; speedup vs baseline: 1.0044x; 1.0044x over previous
//
#include <hip/hip_runtime.h>
#include <hip/hip_bf16.h>
#include <stdint.h>

#define V 23
#define VP 24          // v padded (zeros)
#define KK 3
#define H 8
#define CG 16          // channels per group (in == out)
#define TDIM 256
#define NB 32
#define TT 64          // t-tile
#define OUTC 128
#define CIN 128

// ws layout (floats):
//   [0, 13824)        BnA padded [K][H][VP][VP]
//   [13824, 13952)    scale[128]
//   [13952, 14080)    offs[128]
//   [14080, 20224)    Wt [K][H][C][O]  (transposed conv_w)
#define WS_BNA   0
#define WS_SCALE (KK*H*VP*VP)
#define WS_OFFS  (WS_SCALE + OUTC)
#define WS_WT    (WS_OFFS + OUTC)

static __device__ __forceinline__ uint32_t f2bf_rne(float f) {
  uint32_t u = __float_as_uint(f);
  return (u + 0x7fffu + ((u >> 16) & 1u)) >> 16;
}

// one prep kernel: blocks 0..23 -> BnA, block 24 -> BN fold, blocks 25..48 -> W transpose
__global__ void prep_kernel(const float* __restrict__ emb,
                            const float* __restrict__ A,
                            const float* __restrict__ conv_w,
                            const float* __restrict__ conv_b,
                            const float* __restrict__ gamma,
                            const float* __restrict__ beta,
                            const float* __restrict__ mean,
                            const float* __restrict__ var,
                            const int* __restrict__ hop,
                            int n_hop, float* __restrict__ ws) {
  int b = blockIdx.x;
  int tid = threadIdx.x;
  if (b < KK * H) {                      // BnA for kh = b
    int w = tid;
    if (w >= 32) return;
    const float* e = emb + b * n_hop;
    const float* a = A + b * V * V;
    float nb = 1.f, na = 1.f;
    if (w < V) {
      float sb = 0.f, sa = 0.f;
      for (int v = 0; v < V; ++v) {
        float bv = e[hop[v * V + w]];
        float av = a[v * V + w];
        sb += bv * bv;
        sa += av * av;
      }
      nb = sqrtf(sb) + 1e-4f;
      na = sqrtf(sa) + 1e-4f;
    }
    float* dst = ws + WS_BNA + b * VP * VP;
    if (w < VP) {
      for (int v = 0; v < VP; ++v) {
        float val = 0.f;
        if (v < V && w < V)
          val = e[hop[v * V + w]] / nb + a[v * V + w] / na;
        dst[v * VP + w] = val;
      }
    }
  } else if (b == KK * H) {              // BN fold
    if (tid < OUTC) {
      float inv = gamma[tid] * rsqrtf(var[tid] + 1e-5f);
      float sb = conv_b[tid] + conv_b[OUTC + tid] + conv_b[2 * OUTC + tid];
      ws[WS_SCALE + tid] = inv;
      ws[WS_OFFS + tid] = beta[tid] - mean[tid] * inv + sb * inv;
    }
  } else {                               // W transpose: Wt[k][h][c][o]
    int idx = (b - KK * H - 1) * 256 + tid;
    if (idx < KK * H * CG * CG) {
      int o = idx & 15, c = (idx >> 4) & 15, h = (idx >> 8) & 7, k = idx >> 11;
      ws[WS_WT + ((k * H + h) * CG + c) * CG + o] =
          conv_w[((k * OUTC) + h * CG + o) * CG + c];
    }
  }
}

__global__ __launch_bounds__(256, 3) void gcn_main(
    const float* __restrict__ x,
    const float* __restrict__ ws,
    float* __restrict__ out) {
  // LDS: Xs only = 49152 B -> 3 blocks/CU
  __shared__ __align__(16) uint16_t Xs[CG * TT * VP];   // bf16 [c][tt][vp]

  const int tid = threadIdx.x;
  const int t0 = blockIdx.x * TT;
  const int h  = blockIdx.y;
  const int n  = blockIdx.z;

  // ---- stage x -> bf16 LDS, v padded to 24 with zeros ----
  for (int u = tid; u < CG * TT * 6; u += 256) {
    int c = u / (TT * 6);
    int r = u % (TT * 6);
    int tt = r / 6, vc = r % 6;
    const float* xrow =
        x + ((size_t)((n * CIN + h * CG + c) * TDIM) + (t0 + tt)) * V;
    float f0 = xrow[vc * 4 + 0];
    float f1 = xrow[vc * 4 + 1];
    float f2 = xrow[vc * 4 + 2];
    float f3 = (vc < 5) ? xrow[vc * 4 + 3] : 0.f;   // v=23 pad
    uint32_t lo = f2bf_rne(f0) | (f2bf_rne(f1) << 16);
    uint32_t hi = f2bf_rne(f2) | (f2bf_rne(f3) << 16);
    *(uint2*)&Xs[(c * TT + tt) * VP + vc * 4] = make_uint2(lo, hi);
  }
  __syncthreads();

  // wave-uniform out-channel quad: forces SGPR -> scalar loads for W/BnA
  const int oq = __builtin_amdgcn_readfirstlane(tid >> 6);
  const int tt = tid & 63;

  const float* wt  = ws + WS_WT  + ((size_t)h * CG * CG);        // [k stride KK apart]
  const float* bna = ws + WS_BNA + ((size_t)h * VP * VP);

  float acc[4][VP];
#pragma unroll
  for (int o = 0; o < 4; ++o)
#pragma unroll
    for (int w = 0; w < VP; ++w) acc[o][w] = 0.f;

  for (int k = 0; k < KK; ++k) {
    const float* wtk  = wt  + (size_t)k * H * CG * CG;   // Wt[k][h][c][o]
    const float* bnak = bna + (size_t)k * H * VP * VP;   // BnA[k][h][v][w]
    for (int vb = 0; vb < 3; ++vb) {
      float xwv[4][8];
#pragma unroll
      for (int o = 0; o < 4; ++o)
#pragma unroll
        for (int j = 0; j < 8; ++j) xwv[o][j] = 0.f;

      // stage A: channel mix. W read is wave-uniform -> s_load_dwordx4.
#pragma unroll 4
      for (int c = 0; c < CG; ++c) {
        uint4 raw = *(const uint4*)&Xs[(c * TT + tt) * VP + vb * 8];
        float4 wv = *(const float4*)&wtk[c * CG + (oq << 2)];
        float xv[8];
        xv[0] = __uint_as_float(raw.x << 16);
        xv[1] = __uint_as_float(raw.x & 0xffff0000u);
        xv[2] = __uint_as_float(raw.y << 16);
        xv[3] = __uint_as_float(raw.y & 0xffff0000u);
        xv[4] = __uint_as_float(raw.z << 16);
        xv[5] = __uint_as_float(raw.z & 0xffff0000u);
        xv[6] = __uint_as_float(raw.w << 16);
        xv[7] = __uint_as_float(raw.w & 0xffff0000u);
#pragma unroll
        for (int o = 0; o < 4; ++o) {
          float wo = (&wv.x)[o];
#pragma unroll
          for (int j = 0; j < 8; ++j) xwv[o][j] = fmaf(wo, xv[j], xwv[o][j]);
        }
      }

      // stage B: spatial mix. BnA row reads are wave-uniform -> s_load.
#pragma unroll
      for (int j = 0; j < 8; ++j) {
        const int v = vb * 8 + j;              // v=23 row is zero -> no-op
        const float* bnrow = &bnak[v * VP];
#pragma unroll
        for (int wb = 0; wb < 6; ++wb) {
          float4 bn = *(const float4*)(bnrow + wb * 4);
#pragma unroll
          for (int o = 0; o < 4; ++o) {
            acc[o][wb * 4 + 0] = fmaf(xwv[o][j], bn.x, acc[o][wb * 4 + 0]);
            acc[o][wb * 4 + 1] = fmaf(xwv[o][j], bn.y, acc[o][wb * 4 + 1]);
            acc[o][wb * 4 + 2] = fmaf(xwv[o][j], bn.z, acc[o][wb * 4 + 2]);
            acc[o][wb * 4 + 3] = fmaf(xwv[o][j], bn.w, acc[o][wb * 4 + 3]);
          }
        }
      }
    }
  }

  // ---- epilogue: BN + residual (bf16 from LDS) + relu ----
#pragma unroll
  for (int o = 0; o < 4; ++o) {
    int og = (oq << 2) + o;
    int oc = h * CG + og;
    float sc = ws[WS_SCALE + oc];
    float of = ws[WS_OFFS + oc];
    float* orow = out + ((size_t)(n * OUTC + oc) * TDIM + (t0 + tt)) * V;
    const uint16_t* xsrow = &Xs[(og * TT + tt) * VP];
#pragma unroll
    for (int w = 0; w < V; ++w) {
      float resid = __uint_as_float(((uint32_t)xsrow[w]) << 16);
      float y = fmaf(acc[o][w], sc, of) + resid;
      orow[w] = fmaxf(y, 0.f);
    }
  }
}

extern "C" void kernel_launch(void* const* d_in, const int* in_sizes, int n_in,
                              void* d_out, int out_size, void* d_ws, size_t ws_size,
                              hipStream_t stream) {
  const float* x      = (const float*)d_in[0];
  const float* emb    = (const float*)d_in[1];
  const float* A      = (const float*)d_in[2];
  const float* conv_w = (const float*)d_in[3];
  const float* conv_b = (const float*)d_in[4];
  const float* gamma  = (const float*)d_in[5];
  const float* beta   = (const float*)d_in[6];
  const float* mean   = (const float*)d_in[7];
  const float* var    = (const float*)d_in[8];
  const int*   hop    = (const int*)d_in[9];
  float* ws  = (float*)d_ws;
  float* out = (float*)d_out;

  int n_hop = in_sizes[1] / (KK * H);

  prep_kernel<<<dim3(KK * H + 1 + 24), dim3(256), 0, stream>>>(
      emb, A, conv_w, conv_b, gamma, beta, mean, var, hop, n_hop, ws);
  gcn_main<<<dim3(TDIM / TT, H, NB), dim3(256), 0, stream>>>(x, ws, out);
}

// Round 5
// 247.611 us; speedup vs baseline: 1.1644x; 1.1593x over previous
//
#include <hip/hip_runtime.h>
#include <hip/hip_bf16.h>
#include <stdint.h>

#define V 23
#define VP 24          // v padded with zeros
#define KK 3
#define H 8
#define CG 16          // channels per group (in == out)
#define TDIM 256
#define NB 32
#define TT 64          // t-tile (MFMA M dim = 4 row-tiles of 16)
#define OUTC 128
#define CIN 128
#define KDIM 384       // CG*VP contraction length
#define NSTEP 12       // KDIM/32 MFMA k-steps
#define NCT 24         // 384/16 output col tiles (cols = o*24+w)
#define XROW 392       // LDS A-row stride in bf16 elems (784 B = 49*16, 16B aligned)

// ws layout (float offsets):
#define WS_BNA   0                        // [K][H][VP][VP]
#define WS_SCALE (KK*H*VP*VP)             // 13824
#define WS_OFFS  (WS_SCALE + OUTC)        // 13952
#define WS_WT    (WS_OFFS + OUTC)         // 14080: Wt[k][h][c][o]
#define WS_MB    (WS_WT + KK*H*CG*CG)     // 20224: Mb bf16 [h][s][ct][lane][8]
#define MB_ELEMS ((size_t)H * NSTEP * NCT * 512)          // bf16 elements
#define WS_NEED_BYTES ((size_t)WS_MB * 4 + MB_ELEMS * 2)  // 2,440,192 B
#define WS_SMALL_BYTES ((size_t)WS_MB * 4)                // 80,896 B

typedef __attribute__((ext_vector_type(8))) short bf16x8;
typedef __attribute__((ext_vector_type(4))) float f32x4;

static __device__ __forceinline__ uint32_t f2bf_rne(float f) {
  uint32_t u = __float_as_uint(f);
  return (u + 0x7fffu + ((u >> 16) & 1u)) >> 16;
}
static __device__ __forceinline__ float bf2f(uint16_t h) {
  return __uint_as_float(((uint32_t)h) << 16);
}

// prep1: blocks 0..23 -> BnA, block 24 -> BN fold, blocks 25..48 -> W transpose
__global__ void prep1_kernel(const float* __restrict__ emb,
                             const float* __restrict__ A,
                             const float* __restrict__ conv_w,
                             const float* __restrict__ conv_b,
                             const float* __restrict__ gamma,
                             const float* __restrict__ beta,
                             const float* __restrict__ mean,
                             const float* __restrict__ var,
                             const int* __restrict__ hop,
                             int n_hop, float* __restrict__ ws) {
  int b = blockIdx.x;
  int tid = threadIdx.x;
  if (b < KK * H) {                      // BnA for kh = b
    int w = tid;
    if (w >= 32) return;
    const float* e = emb + b * n_hop;
    const float* a = A + b * V * V;
    float nb = 1.f, na = 1.f;
    if (w < V) {
      float sb = 0.f, sa = 0.f;
      for (int v = 0; v < V; ++v) {
        float bv = e[hop[v * V + w]];
        float av = a[v * V + w];
        sb += bv * bv;
        sa += av * av;
      }
      nb = sqrtf(sb) + 1e-4f;            // l2 over rows (axis=-2), per column
      na = sqrtf(sa) + 1e-4f;
    }
    float* dst = ws + WS_BNA + b * VP * VP;
    if (w < VP) {
      for (int v = 0; v < VP; ++v) {
        float val = 0.f;
        if (v < V && w < V)
          val = e[hop[v * V + w]] / nb + a[v * V + w] / na;
        dst[v * VP + w] = val;
      }
    }
  } else if (b == KK * H) {              // BN fold
    if (tid < OUTC) {
      float inv = gamma[tid] * rsqrtf(var[tid] + 1e-5f);
      float sb = conv_b[tid] + conv_b[OUTC + tid] + conv_b[2 * OUTC + tid];
      ws[WS_SCALE + tid] = inv;
      ws[WS_OFFS + tid] = beta[tid] - mean[tid] * inv + sb * inv;
    }
  } else {                               // Wt[k][h][c][o]
    int idx = (b - KK * H - 1) * 256 + tid;
    if (idx < KK * H * CG * CG) {
      int o = idx & 15, c = (idx >> 4) & 15, h = (idx >> 8) & 7, k = idx >> 11;
      ws[WS_WT + ((k * H + h) * CG + c) * CG + o] =
          conv_w[((k * OUTC) + h * CG + o) * CG + c];
    }
  }
}

// prep2: Mb[h][s][ct][lane][j] bf16 B-fragments for 16x16x32:
//   M[(c,v),(o,w)] = sum_k Wt[k,h,o,c] * BnA[k,h,v,w]
__global__ void prep2_kernel(float* __restrict__ ws) {
  int b = blockIdx.x;                    // 0..95
  int h = b / NSTEP, s = b % NSTEP;
  uint16_t* mb = (uint16_t*)(ws + WS_MB);
  const float* wt = ws + WS_WT;
  const float* bna = ws + WS_BNA;
  for (int e = threadIdx.x; e < NCT * 64 * 8; e += 256) {
    int j = e & 7, lane = (e >> 3) & 63, ct = e >> 9;
    int k = s * 32 + ((lane >> 4) << 3) + j;
    int ci = k / VP, v = k % VP;
    int col = ct * 16 + (lane & 15);
    int o = col / VP, w = col - o * VP;
    float val = 0.f;
    if (v < V && w < V) {
      for (int kk = 0; kk < KK; ++kk)
        val += wt[((kk * H + h) * CG + ci) * CG + o] *
               bna[((kk * H + h) * VP + v) * VP + w];
    }
    mb[((size_t)(h * NSTEP + s) * NCT + ct) * 512 + lane * 8 + j] =
        (uint16_t)f2bf_rne(val);
  }
}

// ---------------- MFMA main (needs full ws) ----------------
__global__ __launch_bounds__(256, 3) void gcn_main_mfma(
    const float* __restrict__ x,
    const float* __restrict__ ws,
    float* __restrict__ out) {
  __shared__ __align__(16) uint16_t Xa[TT * XROW];  // 50176 B -> 3 blocks/CU

  const int tid = threadIdx.x;
  const int t0 = blockIdx.x * TT;
  const int h  = blockIdx.y;
  const int n  = blockIdx.z;

  for (int u = tid; u < CG * TT * 6; u += 256) {
    int c = u / (TT * 6);
    int r = u % (TT * 6);
    int tt = r / 6, vc = r % 6;
    const float* xrow =
        x + ((size_t)((n * CIN + h * CG + c) * TDIM) + (t0 + tt)) * V;
    float f0 = xrow[vc * 4 + 0];
    float f1 = xrow[vc * 4 + 1];
    float f2 = xrow[vc * 4 + 2];
    float f3 = (vc < 5) ? xrow[vc * 4 + 3] : 0.f;
    uint32_t lo = f2bf_rne(f0) | (f2bf_rne(f1) << 16);
    uint32_t hi = f2bf_rne(f2) | (f2bf_rne(f3) << 16);
    *(uint2*)&Xa[tt * XROW + c * VP + vc * 4] = make_uint2(lo, hi);
  }
  __syncthreads();

  const int wave = tid >> 6, lane = tid & 63;
  const int m = lane & 15, q = lane >> 4;

  const uint16_t* mb = (const uint16_t*)(ws + WS_MB) +
                       ((size_t)h * NSTEP * NCT + wave * 6) * 512 + lane * 8;

  f32x4 acc[4][6];
#pragma unroll
  for (int rt = 0; rt < 4; ++rt)
#pragma unroll
    for (int c6 = 0; c6 < 6; ++c6) acc[rt][c6] = (f32x4){0.f, 0.f, 0.f, 0.f};

  for (int s = 0; s < NSTEP; ++s) {
    bf16x8 bf[6];
#pragma unroll
    for (int c6 = 0; c6 < 6; ++c6)
      bf[c6] = *(const bf16x8*)(mb + (size_t)(s * NCT + c6) * 512);
    bf16x8 af[4];
#pragma unroll
    for (int rt = 0; rt < 4; ++rt)
      af[rt] = *(const bf16x8*)&Xa[(rt * 16 + m) * XROW + s * 32 + q * 8];
#pragma unroll
    for (int c6 = 0; c6 < 6; ++c6)
#pragma unroll
      for (int rt = 0; rt < 4; ++rt)
        acc[rt][c6] = __builtin_amdgcn_mfma_f32_16x16x32_bf16(
            af[rt], bf[c6], acc[rt][c6], 0, 0, 0);
  }

#pragma unroll
  for (int c6 = 0; c6 < 6; ++c6) {
    int col = (wave * 6 + c6) * 16 + m;
    int o = col / VP, w = col - o * VP;
    float sc = ws[WS_SCALE + h * CG + o];
    float of = ws[WS_OFFS + h * CG + o];
    bool valid = (w < V);
    float* obase =
        out + ((size_t)(n * OUTC + h * CG + o) * TDIM + t0) * V + w;
#pragma unroll
    for (int rt = 0; rt < 4; ++rt) {
#pragma unroll
      for (int reg = 0; reg < 4; ++reg) {
        int row = rt * 16 + q * 4 + reg;
        float resid = bf2f(Xa[row * XROW + col]);
        float y = fmaf(acc[rt][c6][reg], sc, of) + resid;
        if (valid) obase[(size_t)row * V] = fmaxf(y, 0.f);
      }
    }
  }
}

// ---------------- fallback VALU main (81 KB ws, round-2 proven) ----------------
__global__ __launch_bounds__(256, 3) void gcn_main_valu(
    const float* __restrict__ x,
    const float* __restrict__ ws,
    float* __restrict__ out) {
  __shared__ __align__(16) uint16_t Xs[CG * TT * VP];

  const int tid = threadIdx.x;
  const int t0 = blockIdx.x * TT;
  const int h  = blockIdx.y;
  const int n  = blockIdx.z;

  for (int u = tid; u < CG * TT * 6; u += 256) {
    int c = u / (TT * 6);
    int r = u % (TT * 6);
    int tt = r / 6, vc = r % 6;
    const float* xrow =
        x + ((size_t)((n * CIN + h * CG + c) * TDIM) + (t0 + tt)) * V;
    float f0 = xrow[vc * 4 + 0];
    float f1 = xrow[vc * 4 + 1];
    float f2 = xrow[vc * 4 + 2];
    float f3 = (vc < 5) ? xrow[vc * 4 + 3] : 0.f;
    uint32_t lo = f2bf_rne(f0) | (f2bf_rne(f1) << 16);
    uint32_t hi = f2bf_rne(f2) | (f2bf_rne(f3) << 16);
    *(uint2*)&Xs[(c * TT + tt) * VP + vc * 4] = make_uint2(lo, hi);
  }
  __syncthreads();

  const int oq = __builtin_amdgcn_readfirstlane(tid >> 6);
  const int tt = tid & 63;

  const float* wt  = ws + WS_WT  + ((size_t)h * CG * CG);
  const float* bna = ws + WS_BNA + ((size_t)h * VP * VP);

  float acc[4][VP];
#pragma unroll
  for (int o = 0; o < 4; ++o)
#pragma unroll
    for (int w = 0; w < VP; ++w) acc[o][w] = 0.f;

  for (int k = 0; k < KK; ++k) {
    const float* wtk  = wt  + (size_t)k * H * CG * CG;
    const float* bnak = bna + (size_t)k * H * VP * VP;
    for (int vb = 0; vb < 3; ++vb) {
      float xwv[4][8];
#pragma unroll
      for (int o = 0; o < 4; ++o)
#pragma unroll
        for (int j = 0; j < 8; ++j) xwv[o][j] = 0.f;
#pragma unroll 4
      for (int c = 0; c < CG; ++c) {
        uint4 raw = *(const uint4*)&Xs[(c * TT + tt) * VP + vb * 8];
        float4 wv = *(const float4*)&wtk[c * CG + (oq << 2)];
        float xv[8];
        xv[0] = __uint_as_float(raw.x << 16);
        xv[1] = __uint_as_float(raw.x & 0xffff0000u);
        xv[2] = __uint_as_float(raw.y << 16);
        xv[3] = __uint_as_float(raw.y & 0xffff0000u);
        xv[4] = __uint_as_float(raw.z << 16);
        xv[5] = __uint_as_float(raw.z & 0xffff0000u);
        xv[6] = __uint_as_float(raw.w << 16);
        xv[7] = __uint_as_float(raw.w & 0xffff0000u);
#pragma unroll
        for (int o = 0; o < 4; ++o) {
          float wo = (&wv.x)[o];
#pragma unroll
          for (int j = 0; j < 8; ++j) xwv[o][j] = fmaf(wo, xv[j], xwv[o][j]);
        }
      }
#pragma unroll
      for (int j = 0; j < 8; ++j) {
        const int v = vb * 8 + j;
        const float* bnrow = &bnak[v * VP];
#pragma unroll
        for (int wb = 0; wb < 6; ++wb) {
          float4 bn = *(const float4*)(bnrow + wb * 4);
#pragma unroll
          for (int o = 0; o < 4; ++o) {
            acc[o][wb * 4 + 0] = fmaf(xwv[o][j], bn.x, acc[o][wb * 4 + 0]);
            acc[o][wb * 4 + 1] = fmaf(xwv[o][j], bn.y, acc[o][wb * 4 + 1]);
            acc[o][wb * 4 + 2] = fmaf(xwv[o][j], bn.z, acc[o][wb * 4 + 2]);
            acc[o][wb * 4 + 3] = fmaf(xwv[o][j], bn.w, acc[o][wb * 4 + 3]);
          }
        }
      }
    }
  }

#pragma unroll
  for (int o = 0; o < 4; ++o) {
    int og = (oq << 2) + o;
    int oc = h * CG + og;
    float sc = ws[WS_SCALE + oc];
    float of = ws[WS_OFFS + oc];
    float* orow = out + ((size_t)(n * OUTC + oc) * TDIM + (t0 + tt)) * V;
    const uint16_t* xsrow = &Xs[(og * TT + tt) * VP];
#pragma unroll
    for (int w = 0; w < V; ++w) {
      float resid = bf2f(xsrow[w]);
      float y = fmaf(acc[o][w], sc, of) + resid;
      orow[w] = fmaxf(y, 0.f);
    }
  }
}

extern "C" void kernel_launch(void* const* d_in, const int* in_sizes, int n_in,
                              void* d_out, int out_size, void* d_ws, size_t ws_size,
                              hipStream_t stream) {
  const float* x      = (const float*)d_in[0];
  const float* emb    = (const float*)d_in[1];
  const float* A      = (const float*)d_in[2];
  const float* conv_w = (const float*)d_in[3];
  const float* conv_b = (const float*)d_in[4];
  const float* gamma  = (const float*)d_in[5];
  const float* beta   = (const float*)d_in[6];
  const float* mean   = (const float*)d_in[7];
  const float* var    = (const float*)d_in[8];
  const int*   hop    = (const int*)d_in[9];
  float* ws  = (float*)d_ws;
  float* out = (float*)d_out;

  int n_hop = in_sizes[1] / (KK * H);

  prep1_kernel<<<dim3(KK * H + 1 + 24), dim3(256), 0, stream>>>(
      emb, A, conv_w, conv_b, gamma, beta, mean, var, hop, n_hop, ws);

  if (ws_size >= WS_NEED_BYTES) {
    prep2_kernel<<<dim3(H * NSTEP), dim3(256), 0, stream>>>(ws);
    gcn_main_mfma<<<dim3(TDIM / TT, H, NB), dim3(256), 0, stream>>>(x, ws, out);
  } else {
    gcn_main_valu<<<dim3(TDIM / TT, H, NB), dim3(256), 0, stream>>>(x, ws, out);
  }
}